// Round 7
// baseline (210.486 us; speedup 1.0000x reference)
//
#include <hip/hip_runtime.h>
#include <hip/hip_bf16.h>
#include <cstdint>

// GQA prefill: b=2, t=1024, E=2048, NQ=32, NKV=8, HD=64. fp32 in/out, bf16 MFMA inside.

typedef __attribute__((ext_vector_type(8))) short short8;   // 8 bf16 (MFMA A/B frag)
typedef __attribute__((ext_vector_type(4))) short short4v;
typedef __attribute__((ext_vector_type(4))) float f32x4;    // MFMA C/D frag

__device__ inline short f2b(float f) {  // fp32 -> bf16 (RNE)
  union { float f; unsigned u; } v; v.f = f;
  unsigned r = v.u + 0x7fffu + ((v.u >> 16) & 1u);
  return (short)(r >> 16);
}

__device__ inline float exp2_fast(float x) {
  float r;
  asm("v_exp_f32 %0, %1" : "=v"(r) : "v"(x));
  return r;
}

__device__ inline void gl_lds16(const void* g, void* l) {
  // async global->LDS, 16B/lane; LDS dest = wave-uniform base + lane*16
  __builtin_amdgcn_global_load_lds((const __attribute__((address_space(1))) void*)g,
                                   (__attribute__((address_space(3))) void*)l,
                                   16, 0, 0);
}

// ---------------- prep: x cast + all weight transposes in ONE launch ----------------
// bx < nCast: cast 1024 floats/block. Else: 64x64 transpose tiles (80 x-tiles, 32 k-tiles).
__global__ void prep_kernel(const float* __restrict__ x,
                            const float* __restrict__ wq, const float* __restrict__ wk,
                            const float* __restrict__ wv, const float* __restrict__ wo,
                            short* __restrict__ xb, short* __restrict__ WqkvT,
                            short* __restrict__ woT, int nCast) {
  const int bx = blockIdx.x;
  const int tid = threadIdx.x;
  if (bx < nCast) {
    int i = bx * 256 + tid;
    float4 v = ((const float4*)x)[i];
    short4v o; o.x = f2b(v.x); o.y = f2b(v.y); o.z = f2b(v.z); o.w = f2b(v.w);
    ((short4v*)xb)[i] = o;
    return;
  }
  __shared__ float tile[64][65];
  const int id = bx - nCast;
  const int wx = id % 80, ky = id / 80;
  const float* W; short* WT; int N, off, nb;
  if (wx < 32)      { W = wq; WT = WqkvT; N = 2048; off = 0;    nb = wx * 64; }
  else if (wx < 40) { W = wk; WT = WqkvT; N = 512;  off = 2048; nb = (wx - 32) * 64; }
  else if (wx < 48) { W = wv; WT = WqkvT; N = 512;  off = 2560; nb = (wx - 40) * 64; }
  else              { W = wo; WT = woT;   N = 2048; off = 0;    nb = (wx - 48) * 64; }
  const int kb = ky * 64;
  const int c = tid & 63, r0 = tid >> 6;
#pragma unroll
  for (int s = 0; s < 16; ++s) {
    int k = r0 + s * 4;
    tile[c][k] = W[(size_t)(kb + k) * N + nb + c];
  }
  __syncthreads();
#pragma unroll
  for (int s = 0; s < 16; ++s) {
    int n = r0 + s * 4;
    WT[(size_t)(off + nb + n) * 2048 + kb + c] = f2b(tile[n][c]);
  }
}

// ---------------- shared K-loop: 128(M)x64(N) tile, K=2048, BK=64, double-buffered ----------
__device__ __forceinline__ void gemm_loop_bk64(const short* __restrict__ Ag,
                                               const short* __restrict__ Bg,
                                               short* lA, short* lB,
                                               int w, int l15, int q4,
                                               f32x4 acc[2][4]) {
  const int K = 2048, NS = 32;  // stages of BK=64
  auto stage = [&](int s, int d) {
    const short* As = Ag + s * 64;
    const short* Bs = Bg + s * 64;
    short* a = lA + d * 8192 + w * 512;
    gl_lds16(As, a);
    gl_lds16(As + 64 * K, a + 2048);
    gl_lds16(As + 32, a + 4096);
    gl_lds16(As + 64 * K + 32, a + 6144);
    short* bp = lB + d * 4096 + w * 512;
    gl_lds16(Bs, bp);
    gl_lds16(Bs + 32, bp + 2048);
  };
  stage(0, 0);
  for (int s = 0; s < NS; ++s) {
    const int d = s & 1;
    __syncthreads();
    if (s + 1 < NS) stage(s + 1, d ^ 1);
#pragma unroll
    for (int ks = 0; ks < 2; ++ks) {
      const short* ap = lA + d * 8192 + ks * 4096;
      const short* bp = lB + d * 4096 + ks * 2048;
      short8 af[2], bf[4];
#pragma unroll
      for (int mf = 0; mf < 2; ++mf) af[mf] = *(const short8*)(ap + (w * 32 + mf * 16 + l15) * 32 + q4 * 8);
#pragma unroll
      for (int nf = 0; nf < 4; ++nf) bf[nf] = *(const short8*)(bp + (nf * 16 + l15) * 32 + q4 * 8);
#pragma unroll
      for (int mf = 0; mf < 2; ++mf)
#pragma unroll
        for (int nf = 0; nf < 4; ++nf)
          acc[mf][nf] = __builtin_amdgcn_mfma_f32_16x16x32_bf16(af[mf], bf[nf], acc[mf][nf], 0, 0, 0);
    }
  }
}

// ---------------- fused QKV GEMM + bias + RoPE + scatter epilogue (V -> VT panels direct) ----
__launch_bounds__(256, 3)
__global__ void gemm_qkv(const short* __restrict__ A, const short* __restrict__ BT,
                         const float* __restrict__ bq, const float* __restrict__ bk,
                         const float* __restrict__ bv,
                         short* __restrict__ Qb, short* __restrict__ Kb,
                         short* __restrict__ VTb) {
  __shared__ __align__(16) short lA[16384];
  __shared__ __align__(16) short lB[8192];
  const int K = 2048;
  const int tid = threadIdx.x, lane = tid & 63, w = tid >> 6;
  const int q4 = lane >> 4, l15 = lane & 15;
  const int bn = blockIdx.x * 64, bm = blockIdx.y * 128;

  const short* Ag = A + (size_t)(bm + (tid >> 2)) * K + ((tid & 3) << 3);
  const short* Bg = BT + (size_t)(bn + (tid >> 2)) * K + ((tid & 3) << 3);

  f32x4 acc[2][4];
  const f32x4 fz = {0.f, 0.f, 0.f, 0.f};
#pragma unroll
  for (int i = 0; i < 2; ++i)
#pragma unroll
    for (int j = 0; j < 4; ++j) acc[i][j] = fz;

  gemm_loop_bk64(Ag, Bg, lA, lB, w, l15, q4, acc);

  // ----- epilogue -----
  const float L2T = 0.4152410118609203f;          // log2(10000)/32
  const float theta_a = exp2_fast(-(float)l15 * L2T);
  const float theta_b = exp2_fast(-(float)(l15 + 16) * L2T);
  const float s2 = 0.18033688011112042f;          // 0.125 * log2(e): base-2 attn scores

  if (bn < 2048) {            // ---- Q: rope + scale -> Qb (b,h,t,64)
    const int h = bn >> 6;
    float bb0 = bq[bn + l15], bb1 = bq[bn + 16 + l15], bb2 = bq[bn + 32 + l15], bb3 = bq[bn + 48 + l15];
#pragma unroll
    for (int mf = 0; mf < 2; ++mf)
#pragma unroll
      for (int r = 0; r < 4; ++r) {
        int row = bm + w * 32 + mf * 16 + q4 * 4 + r;
        int batch = row >> 10, t = row & 1023;
        float pos = (float)(t + 1);
        float sa, ca, sb, cb;
        __sincosf(pos * theta_a, &sa, &ca);
        __sincosf(pos * theta_b, &sb, &cb);
        float x0 = acc[mf][0][r] + bb0, x2 = acc[mf][2][r] + bb2;
        float x1 = acc[mf][1][r] + bb1, x3 = acc[mf][3][r] + bb3;
        size_t base = ((size_t)(batch * 32 + h) * 1024 + t) * 64;
        Qb[base + l15]      = f2b((x0 * ca - x2 * sa) * s2);
        Qb[base + l15 + 32] = f2b((x2 * ca + x0 * sa) * s2);
        Qb[base + l15 + 16] = f2b((x1 * cb - x3 * sb) * s2);
        Qb[base + l15 + 48] = f2b((x3 * cb + x1 * sb) * s2);
      }
  } else if (bn < 2560) {     // ---- K: rope -> Kb (b,hkv)[dhalf][t][32]
    const int co = bn - 2048;
    const int hkv = co >> 6;
    float bb0 = bk[co + l15], bb1 = bk[co + 16 + l15], bb2 = bk[co + 32 + l15], bb3 = bk[co + 48 + l15];
#pragma unroll
    for (int mf = 0; mf < 2; ++mf)
#pragma unroll
      for (int r = 0; r < 4; ++r) {
        int row = bm + w * 32 + mf * 16 + q4 * 4 + r;
        int batch = row >> 10, t = row & 1023;
        float pos = (float)(t + 1);
        float sa, ca, sb, cb;
        __sincosf(pos * theta_a, &sa, &ca);
        __sincosf(pos * theta_b, &sb, &cb);
        float x0 = acc[mf][0][r] + bb0, x2 = acc[mf][2][r] + bb2;
        float x1 = acc[mf][1][r] + bb1, x3 = acc[mf][3][r] + bb3;
        size_t base = (size_t)(batch * 8 + hkv) * 65536 + t * 32;
        Kb[base + l15]              = f2b(x0 * ca - x2 * sa);
        Kb[base + l15 + 16]         = f2b(x1 * cb - x3 * sb);
        Kb[base + 32768 + l15]      = f2b(x2 * ca + x0 * sa);
        Kb[base + 32768 + l15 + 16] = f2b(x3 * cb + x1 * sb);
      }
  } else {                    // ---- V: bias -> VT panels (b,hkv)[tchunk32][d64][32] DIRECT
    const int co = bn - 2560;
    const int hkv = co >> 6;
    float bb[4];
#pragma unroll
    for (int nf = 0; nf < 4; ++nf) bb[nf] = bv[co + nf * 16 + l15];
#pragma unroll
    for (int mf = 0; mf < 2; ++mf) {
      int row0 = bm + w * 32 + mf * 16 + q4 * 4;     // r = 0
      int batch = row0 >> 10, t0 = row0 & 1023;
      size_t base = (size_t)(batch * 8 + hkv) * 65536 + (size_t)(t0 >> 5) * 2048 + (t0 & 31);
#pragma unroll
      for (int nf = 0; nf < 4; ++nf) {
        short4v pk;
#pragma unroll
        for (int r = 0; r < 4; ++r) pk[r] = f2b(acc[mf][nf][r] + bb[nf]);
        *(short4v*)(VTb + base + (nf * 16 + l15) * 32) = pk;
      }
    }
  }
}

// ---------------- flash attention v6: 64-k stages, double-buffered prefetch ----------------
// grid (8, 32, B); block = 128 q-rows; wave w owns rows [qt*128+w*32, +32).
// Stage = 64 k-cols: K (2 dhalf x 64 x 32 = 8KB) + V^T (2 tchunk x 64 x 32 = 8KB), dbuf.
// One barrier per stage; stage s+1 prefetched before computing stage s (loads age a full
// compute phase before the barrier drain). Fixed-shift softmax P = 2^(s2-16), linear state.
#define PROW 72
__launch_bounds__(256, 3)
__global__ void attn6_kernel(const short* __restrict__ Qb, const short* __restrict__ Kb,
                             const short* __restrict__ VTb, short* __restrict__ AO) {
  __shared__ __align__(16) short lK[2][4096];   // [buf][dhalf(2) x 64 x 32]
  __shared__ __align__(16) short lV[2][4096];   // [buf][tchunk(2) x 64 x 32]
  __shared__ __align__(16) short lP[4][16 * PROW];
  const int tid = threadIdx.x, lane = tid & 63, w = tid >> 6;
  const int q4 = lane >> 4, l15 = lane & 15;
  const int qt = (int)gridDim.x - 1 - (int)blockIdx.x;  // heavy blocks first
  const int h = blockIdx.y, b = blockIdx.z;
  const int hkv = h >> 2;
  const int qb = qt * 128 + w * 32;
  const int kdiag = qb >> 6;            // wave's diagonal 64-tile index
  const int ns = qt * 2 + 2;            // 64-k stages (uniform in block)

  const short* Qg = Qb + (size_t)(b * 32 + h) * 65536;
  const short* Kg = Kb + (size_t)(b * 8 + hkv) * 65536;
  const short* Vg = VTb + (size_t)(b * 8 + hkv) * 65536;
  short* lPw = lP[w];

  short8 qf[2][2];
#pragma unroll
  for (int mf = 0; mf < 2; ++mf) {
    const short* qr = Qg + (size_t)(qb + mf * 16 + l15) * 64 + q4 * 8;
    qf[mf][0] = *(const short8*)(qr);
    qf[mf][1] = *(const short8*)(qr + 32);
  }

  const f32x4 fz = {0.f, 0.f, 0.f, 0.f};
  f32x4 o[2][4], ol[2];
#pragma unroll
  for (int mf = 0; mf < 2; ++mf) {
    ol[mf] = fz;
#pragma unroll
    for (int i = 0; i < 4; ++i) o[mf][i] = fz;
  }
  short8 ones;
#pragma unroll
  for (int i = 0; i < 8; ++i) ones[i] = (short)0x3F80;

  // wave w stages chunks j = w*4..w*4+3 (1KB each): j<8 -> K, else V
  auto stage = [&](int s, int d) {
#pragma unroll
    for (int c = 0; c < 4; ++c) {
      int j = w * 4 + c;
      if (j < 8) {
        const short* src = Kg + (size_t)(j >> 2) * 32768 + s * 2048 + (j & 3) * 512 + lane * 8;
        gl_lds16(src, &lK[d][j * 512]);
      } else {
        int jj = j - 8;
        const short* src = Vg + (size_t)(s * 2 + (jj >> 2)) * 2048 + (jj & 3) * 512 + lane * 8;
        gl_lds16(src, &lV[d][jj * 512]);
      }
    }
  };

  stage(0, 0);
  for (int s = 0; s < ns; ++s) {
    const int d = s & 1;
    __syncthreads();                       // drains stage(s); frees buf d^1 for prefetch
    if (s + 1 < ns) stage(s + 1, d ^ 1);
    if (s <= kdiag) {
      short8 kf0[4], kf1[4], vf0[4], vf1[4];
#pragma unroll
      for (int nt = 0; nt < 4; ++nt) {
        kf0[nt] = *(const short8*)(&lK[d][(nt * 16 + l15) * 32 + q4 * 8]);
        kf1[nt] = *(const short8*)(&lK[d][2048 + (nt * 16 + l15) * 32 + q4 * 8]);
        vf0[nt] = *(const short8*)(&lV[d][(nt * 16 + l15) * 32 + q4 * 8]);
        vf1[nt] = *(const short8*)(&lV[d][2048 + (nt * 16 + l15) * 32 + q4 * 8]);
      }
      const bool diag = (s == kdiag);
#pragma unroll
      for (int mf = 0; mf < 2; ++mf) {
        f32x4 sv[4];
#pragma unroll
        for (int nt = 0; nt < 4; ++nt) {
          f32x4 z = __builtin_amdgcn_mfma_f32_16x16x32_bf16(qf[mf][0], kf0[nt], fz, 0, 0, 0);
          sv[nt] = __builtin_amdgcn_mfma_f32_16x16x32_bf16(qf[mf][1], kf1[nt], z, 0, 0, 0);
        }
        if (diag) {
#pragma unroll
          for (int r = 0; r < 4; ++r) {
            const int qrow = qb + mf * 16 + q4 * 4 + r;
            const int col = s * 64 + l15;
#pragma unroll
            for (int nt = 0; nt < 4; ++nt)
              if (col + nt * 16 > qrow) sv[nt][r] = -1e30f;
          }
        }
#pragma unroll
        for (int r = 0; r < 4; ++r)
#pragma unroll
          for (int nt = 0; nt < 4; ++nt)
            lPw[(q4 * 4 + r) * PROW + nt * 16 + l15] = f2b(exp2_fast(sv[nt][r] - 16.f));

        short8 pf0 = *(const short8*)(lPw + l15 * PROW + q4 * 8);
        short8 pf1 = *(const short8*)(lPw + l15 * PROW + 32 + q4 * 8);
        ol[mf] = __builtin_amdgcn_mfma_f32_16x16x32_bf16(pf0, ones, ol[mf], 0, 0, 0);
        ol[mf] = __builtin_amdgcn_mfma_f32_16x16x32_bf16(pf1, ones, ol[mf], 0, 0, 0);
#pragma unroll
        for (int dt = 0; dt < 4; ++dt) {
          o[mf][dt] = __builtin_amdgcn_mfma_f32_16x16x32_bf16(pf0, vf0[dt], o[mf][dt], 0, 0, 0);
          o[mf][dt] = __builtin_amdgcn_mfma_f32_16x16x32_bf16(pf1, vf1[dt], o[mf][dt], 0, 0, 0);
        }
      }
    }
  }

#pragma unroll
  for (int mf = 0; mf < 2; ++mf)
#pragma unroll
    for (int r = 0; r < 4; ++r) {
      float inv = __builtin_amdgcn_rcpf(ol[mf][r]);
      int row = qb + mf * 16 + q4 * 4 + r;
#pragma unroll
      for (int dt = 0; dt < 4; ++dt)
        AO[(size_t)(b * 1024 + row) * 2048 + h * 64 + dt * 16 + l15] = f2b(o[mf][dt][r] * inv);
    }
}

// ---------------- output projection: BK=64 double-buffered, fp32 out + bias ----------------
__launch_bounds__(256, 3)
__global__ void gemm_out(const short* __restrict__ A, const short* __restrict__ BT,
                         float* __restrict__ C, const float* __restrict__ bias,
                         int N, int K) {
  __shared__ __align__(16) short lA[16384];
  __shared__ __align__(16) short lB[8192];
  const int tid = threadIdx.x, lane = tid & 63, w = tid >> 6;
  const int q4 = lane >> 4, l15 = lane & 15;
  const int bn = blockIdx.x * 64, bm = blockIdx.y * 128;

  const short* Ag = A + (size_t)(bm + (tid >> 2)) * K + ((tid & 3) << 3);
  const short* Bg = BT + (size_t)(bn + (tid >> 2)) * K + ((tid & 3) << 3);

  f32x4 acc[2][4];
  const f32x4 fz = {0.f, 0.f, 0.f, 0.f};
#pragma unroll
  for (int i = 0; i < 2; ++i)
#pragma unroll
    for (int j = 0; j < 4; ++j) acc[i][j] = fz;

  gemm_loop_bk64(Ag, Bg, lA, lB, w, l15, q4, acc);

#pragma unroll
  for (int mf = 0; mf < 2; ++mf)
#pragma unroll
    for (int nf = 0; nf < 4; ++nf) {
      int col = bn + nf * 16 + l15;
      float bb = bias[col];
#pragma unroll
      for (int r = 0; r < 4; ++r) {
        int row = bm + w * 32 + mf * 16 + q4 * 4 + r;
        C[(size_t)row * N + col] = acc[mf][nf][r] + bb;
      }
    }
}

extern "C" void kernel_launch(void* const* d_in, const int* in_sizes, int n_in,
                              void* d_out, int out_size, void* d_ws, size_t ws_size,
                              hipStream_t stream) {
  const float* x  = (const float*)d_in[0];
  const float* wq = (const float*)d_in[1];
  const float* bq = (const float*)d_in[2];
  const float* wk = (const float*)d_in[3];
  const float* bk = (const float*)d_in[4];
  const float* wv = (const float*)d_in[5];
  const float* bv = (const float*)d_in[6];
  const float* wo = (const float*)d_in[7];
  const float* bo = (const float*)d_in[8];
  float* out = (float*)d_out;
  const int B = in_sizes[0] / (1024 * 2048);
  const int M = B * 1024;

  char* ws = (char*)d_ws;
  size_t off = 0;
  auto alloc = [&](size_t bytes) -> char* {
    char* p = ws + off;
    off += (bytes + 255) & ~(size_t)255;
    return p;
  };
  short* xb    = (short*)alloc((size_t)M * 2048 * 2);
  short* WqkvT = (short*)alloc((size_t)3072 * 2048 * 2);  // rows: wq^T | wk^T | wv^T (K-major)
  short* woT   = (short*)alloc((size_t)2048 * 2048 * 2);
  short* Qb    = (short*)alloc((size_t)B * 32 * 1024 * 64 * 2);    // (b,h,t,d)
  short* Kb    = (short*)alloc((size_t)B * 8 * 2 * 1024 * 32 * 2); // (b,hkv)[dhalf][t][32]
  short* VTb   = (short*)alloc((size_t)B * 8 * 32 * 64 * 32 * 2);  // (b,hkv)[tchunk][d][32]
  short* AO    = (short*)alloc((size_t)M * 2048 * 2);              // (b,t,E) bf16

  const int nCast = M * 2048 / 1024;  // cast blocks (1024 floats each)
  prep_kernel<<<nCast + 80 * 32, 256, 0, stream>>>(x, wq, wk, wv, wo, xb, WqkvT, woT, nCast);
  gemm_qkv<<<dim3(48, M / 128), 256, 0, stream>>>(xb, WqkvT, bq, bk, bv, Qb, Kb, VTb);
  attn6_kernel<<<dim3(8, 32, B), 256, 0, stream>>>(Qb, Kb, VTb, AO);
  gemm_out<<<dim3(32, M / 128), 256, 0, stream>>>(AO, woT, out, bo, 2048, 2048);
}